// Round 1
// baseline (101.468 us; speedup 1.0000x reference)
//
#include <hip/hip_runtime.h>

#define IS 256
#define FNUM 4096
#define BATCH 2
#define FAR_ 100.0f
#define NEAR_ 0.1f

// LDS record layout (20 floats per surviving face):
// 0..5 : x0 y0 x1 y1 x2 y2
// 6..14: inv matrix rows (already divided by clamped det)
// 15..17: z0 z1 z2
// 18   : face id (bit-cast int)
// 19   : pad (keeps 16B alignment of records: 80B each)

__global__ __launch_bounds__(256) void raster_kernel(
    const float* __restrict__ faces, const float* __restrict__ tex,
    float* __restrict__ out_rgb, float* __restrict__ out_alpha,
    float* __restrict__ out_z)
{
#pragma clang fp contract(off)
  __shared__ float rec[256 * 20];
  __shared__ int cnt[4];

  const int tx = threadIdx.x, ty = threadIdx.y;
  const int tid = ty * 16 + tx;
  const int wid = tid >> 6, lane = tid & 63;
  const int b = blockIdx.z;
  const int col = blockIdx.x * 16 + tx;
  const int row = blockIdx.y * 16 + ty;

  // pixel centers: c[i] = (2i+1-256)/256 ; xp = c[col], yp = -c[row]
  const float xp = (2.0f * (float)col + 1.0f - 256.0f) * (1.0f / 256.0f);
  const float yp = -((2.0f * (float)row + 1.0f - 256.0f) * (1.0f / 256.0f));

  // tile bounds in NDC (pixel centers), with conservative margin
  const float txmin = (2.0f * (float)(blockIdx.x * 16) + 1.0f - 256.0f) * (1.0f / 256.0f) - 1e-3f;
  const float txmax = (2.0f * (float)(blockIdx.x * 16 + 15) + 1.0f - 256.0f) * (1.0f / 256.0f) + 1e-3f;
  const float tymax = -((2.0f * (float)(blockIdx.y * 16) + 1.0f - 256.0f) * (1.0f / 256.0f)) + 1e-3f;
  const float tymin = -((2.0f * (float)(blockIdx.y * 16 + 15) + 1.0f - 256.0f) * (1.0f / 256.0f)) - 1e-3f;

  float bz = FAR_;
  float bw0 = 0.f, bw1 = 0.f, bw2 = 0.f;
  float bz0 = 1.f, bz1 = 1.f, bz2 = 1.f;
  int bfid = -1;

  for (int ch = 0; ch < FNUM; ch += 256) {
    const int f = ch + tid;
    const float* fp = faces + ((size_t)b * FNUM + f) * 9;
    const float x0 = fp[0], y0 = fp[1], z0 = fp[2];
    const float x1 = fp[3], y1 = fp[4], z1 = fp[5];
    const float x2 = fp[6], y2 = fp[7], z2 = fp[8];

    const float det = x2 * (y0 - y1) + x0 * (y1 - y2) + x1 * (y2 - y0);
    const float minx = fminf(fminf(x0, x1), x2), maxx = fmaxf(fmaxf(x0, x1), x2);
    const float miny = fminf(fminf(y0, y1), y2), maxy = fmaxf(fmaxf(y0, y1), y2);
    // det < -1e-5: the three half-planes (e>=0) have empty intersection even
    // under fp noise (e01+e12+e20 == det, per-edge fp error ~5e-7).
    const bool keep = (det >= -1e-5f) &&
                      (minx <= txmax) && (maxx >= txmin) &&
                      (miny <= tymax) && (maxy >= tymin);

    const unsigned long long m = __ballot(keep);
    if (lane == 0) cnt[wid] = __popcll(m);
    __syncthreads();  // cnt visible; also fences prior inner-loop reads of rec
    const int total = cnt[0] + cnt[1] + cnt[2] + cnt[3];
    if (keep) {
      int base = 0;
      for (int w = 0; w < wid; ++w) base += cnt[w];
      const int pos = base + __popcll(m & ((1ull << lane) - 1ull));
      const float cd = (det >= 0.0f) ? fmaxf(det, 1e-10f) : fminf(det, -1e-10f);
      float* r = &rec[pos * 20];
      r[0] = x0; r[1] = y0; r[2] = x1; r[3] = y1; r[4] = x2; r[5] = y2;
      r[6]  = (y1 - y2) / cd; r[7]  = (x2 - x1) / cd; r[8]  = (x1 * y2 - x2 * y1) / cd;
      r[9]  = (y2 - y0) / cd; r[10] = (x0 - x2) / cd; r[11] = (x2 * y0 - x0 * y2) / cd;
      r[12] = (y0 - y1) / cd; r[13] = (x1 - x0) / cd; r[14] = (x0 * y1 - x1 * y0) / cd;
      r[15] = z0; r[16] = z1; r[17] = z2;
      r[18] = __int_as_float(f);
      r[19] = 0.f;
    }
    __syncthreads();  // rec visible

    for (int i = 0; i < total; ++i) {
      const float* r = &rec[i * 20];
      const float fx0 = r[0], fy0 = r[1], fx1 = r[2], fy1 = r[3], fx2 = r[4], fy2 = r[5];
      const float e01 = (yp - fy0) * (fx1 - fx0) - (xp - fx0) * (fy1 - fy0);
      const float e12 = (yp - fy1) * (fx2 - fx1) - (xp - fx1) * (fy2 - fy1);
      const float e20 = (yp - fy2) * (fx0 - fx2) - (xp - fx2) * (fy0 - fy2);
      if (e01 >= 0.0f && e12 >= 0.0f && e20 >= 0.0f) {
        float w0 = (r[6]  * xp + r[7]  * yp) + r[8];
        float w1 = (r[9]  * xp + r[10] * yp) + r[11];
        float w2 = (r[12] * xp + r[13] * yp) + r[14];
        w0 = fminf(fmaxf(w0, 0.0f), 1.0f);
        w1 = fminf(fmaxf(w1, 0.0f), 1.0f);
        w2 = fminf(fmaxf(w2, 0.0f), 1.0f);
        const float s = fmaxf((w0 + w1) + w2, 1e-10f);
        w0 = w0 / s; w1 = w1 / s; w2 = w2 / s;
        const float fz0 = r[15], fz1 = r[16], fz2 = r[17];
        const float izp = ((w0 / fz0) + (w1 / fz1)) + (w2 / fz2);
        const float zp = 1.0f / fmaxf(izp, 1e-10f);
        if (zp > NEAR_ && zp < FAR_ && zp < bz) {
          bz = zp;
          bw0 = w0; bw1 = w1; bw2 = w2;
          bz0 = fz0; bz1 = fz1; bz2 = fz2;
          bfid = __float_as_int(r[18]);
        }
      }
    }
  }

  float rr = 0.f, rg = 0.f, rb = 0.f;
  float alpha = 0.f;
  if (bfid >= 0) {
    alpha = 1.0f;
    // tif = clip((w * 3) * (zp / fz), 0, 2.999)
    const float t0 = fminf(fmaxf((bw0 * 3.0f) * (bz / bz0), 0.0f), 2.999f);
    const float t1 = fminf(fmaxf((bw1 * 3.0f) * (bz / bz1), 0.0f), 2.999f);
    const float t2 = fminf(fmaxf((bw2 * 3.0f) * (bz / bz2), 0.0f), 2.999f);
    const float l0 = floorf(t0), l1 = floorf(t1), l2 = floorf(t2);
    const int i0 = (int)l0, i1 = (int)l1, i2 = (int)l2;
    const float fr0 = t0 - l0, fr1 = t1 - l1, fr2 = t2 - l2;
    const float* tb = tex + ((size_t)b * FNUM + bfid) * 192;  // 64 texels * 3
    for (int pn = 0; pn < 8; ++pn) {
      const int b0 = pn & 1, b1 = (pn >> 1) & 1, b2 = (pn >> 2) & 1;
      const float c0 = b0 ? fr0 : (1.0f - fr0);
      const float c1 = b1 ? fr1 : (1.0f - fr1);
      const float c2 = b2 ? fr2 : (1.0f - fr2);
      const float wc = (c0 * c1) * c2;
      const int lin = ((i0 + b0) * 4 + (i1 + b1)) * 4 + (i2 + b2);
      const float* tp = tb + lin * 3;
      rr = rr + wc * tp[0];
      rg = rg + wc * tp[1];
      rb = rb + wc * tp[2];
    }
  }

  const size_t pix = (size_t)b * (IS * IS) + (size_t)row * IS + col;
  out_rgb[pix * 3 + 0] = rr;
  out_rgb[pix * 3 + 1] = rg;
  out_rgb[pix * 3 + 2] = rb;
  out_alpha[pix] = alpha;
  out_z[pix] = bz;
}

extern "C" void kernel_launch(void* const* d_in, const int* in_sizes, int n_in,
                              void* d_out, int out_size, void* d_ws, size_t ws_size,
                              hipStream_t stream) {
  const float* faces = (const float*)d_in[0];     // (2,4096,3,3)
  const float* tex   = (const float*)d_in[1];     // (2,4096,4,4,4,3)
  float* out = (float*)d_out;
  float* out_rgb   = out;                          // 2*256*256*3 = 393216
  float* out_alpha = out + 393216;                 // 2*256*256   = 131072
  float* out_z     = out + 393216 + 131072;

  dim3 grid(IS / 16, IS / 16, BATCH);
  dim3 block(16, 16, 1);
  hipLaunchKernelGGL(raster_kernel, grid, block, 0, stream,
                     faces, tex, out_rgb, out_alpha, out_z);
}